// Round 3
// baseline (475.060 us; speedup 1.0000x reference)
//
#include <hip/hip_runtime.h>
#include <hip/hip_bf16.h>

#define EPS 1e-6f

typedef __attribute__((ext_vector_type(8))) __bf16 bf16x8;
typedef __attribute__((ext_vector_type(4))) float f32x4;
typedef __attribute__((ext_vector_type(4))) unsigned short us4v;
typedef __attribute__((ext_vector_type(8))) unsigned short us8v;
typedef __attribute__((ext_vector_type(4))) unsigned int ui4v;
typedef unsigned short us;

__device__ inline us f2bf(float f) {
  unsigned int u = __builtin_bit_cast(unsigned int, f);
  unsigned int r = (u + 0x7fffu + ((u >> 16) & 1u)) >> 16;
  return (us)r;
}
__device__ inline float bf2f(us s) {
  unsigned int u = ((unsigned int)s) << 16;
  return __builtin_bit_cast(float, u);
}
// packed f32x2 -> bf16x2 (RNE); lowers to v_cvt_pk_bf16_f32 on gfx950
__device__ inline unsigned int pk2(float a, float b) {
  if constexpr (sizeof(__hip_bfloat162) == 4) {
    __hip_bfloat162 h = __float22bfloat162_rn(make_float2(a, b));
    unsigned int u;
    __builtin_memcpy(&u, &h, 4);
    return u;
  } else {
    return (unsigned int)f2bf(a) | ((unsigned int)f2bf(b) << 16);
  }
}

__device__ inline void gl_lds16(const us* g, us* l) {
  __builtin_amdgcn_global_load_lds(
      (const __attribute__((address_space(1))) unsigned int*)g,
      (__attribute__((address_space(3))) unsigned int*)l, 16, 0, 0);
}

// ---------------------------------------------------------------------------
// fp32 -> bf16 convert (weights only now). grid = n/2048.
// ---------------------------------------------------------------------------
__global__ __launch_bounds__(256) void conv_bf16(const float* __restrict__ s,
                                                 us* __restrict__ d) {
  int idx = blockIdx.x * 256 + threadIdx.x;
  size_t base = (size_t)idx * 8;
  float4 a = *(const float4*)(s + base);
  float4 b = *(const float4*)(s + base + 4);
  unsigned int p0 = pk2(a.x, a.y), p1 = pk2(a.z, a.w);
  unsigned int p2 = pk2(b.x, b.y), p3 = pk2(b.z, b.w);
  *(ui4v*)(d + base) = (ui4v){p0, p1, p2, p3};
}

// ---------------------------------------------------------------------------
// Projection GEMM, 128x128 tile, BK=64, mfma 16x16x32 bf16.
// Y[i][j] = act( sum_k X[i][k] * W[j][k] + bias[j] )
// MODE 0: X fp32; FUSED q-projection + linear attention; bf16 row-major attn out
// MODE 1: X fp32; phi; bf16 transposed-per-head out (kt[bh][d][m]) via LDS
// MODE 2: X fp32; identity; vt[bh][e][m] via LDS
// MODE 3: X bf16 (gl_lds staging); identity; fp32 row-major out
// grid 1024 1-D: col=bid>>7, row=bid&127 (8 col-blocks of a row share an XCD).
// ---------------------------------------------------------------------------
template <int MODE>
__global__ __launch_bounds__(256) void proj_gemm(const void* __restrict__ Xv,
                                                 const us* __restrict__ W,
                                                 const float* __restrict__ bias,
                                                 void* __restrict__ Yv,
                                                 const us* __restrict__ kvb,
                                                 const float* __restrict__ zg) {
  constexpr int SMU = (MODE == 0) ? 25600 : 16384;
  __shared__ alignas(16) us smem[SMU];
  __shared__ float fbuf[(MODE == 0) ? 512 : 4];
  us* Xs = smem;              // 128 x 64 bf16, 16B-chunk XOR swizzled
  us* Ws = smem + 8192;
  us* tile = smem;            // 32KB epilogue overlay (modes 0/1/2)
  us* kvs = smem + 16384;     // MODE 0: 2 heads x 64x72

  const int t = threadIdx.x;
  const int wave = t >> 6, lane = t & 63;
  const int q4 = lane >> 4, l16 = lane & 15;
  const int wm = wave & 1, wn = wave >> 1;
  const int bid = blockIdx.x;
  const int colBase = (bid >> 7) << 7;
  const int rowBase = (bid & 127) << 7;
  const int b = rowBase >> 12;

  // MODE 0 prologue: kv, z, bias into LDS (kv ready before this kernel runs)
  if (MODE == 0) {
    const int h0 = colBase >> 6;
    const size_t kvbase = ((size_t)(b * 16 + h0)) << 12;
#pragma unroll
    for (int i = 0; i < 4; i++) {
      int c = t + 256 * i;              // 0..1023 chunks of 8
      int head = c >> 9, rem = c & 511;
      us8v v = *(const us8v*)&kvb[kvbase + ((size_t)head << 12) + rem * 8];
      *(us8v*)&kvs[head * 4608 + (rem >> 3) * 72 + (rem & 7) * 8] = v;
    }
    if (t < 128) {
      fbuf[256 + t] = zg[(b * 16 + h0 + (t >> 6)) * 64 + (t & 63)];  // zs
      fbuf[384 + t] = bias[colBase + t];                              // bias
    }
  }

  // gl_lds staging geometry (W always; X too in MODE 3)
  const int srow0 = t >> 3;
  const int spos8 = ((t & 7) ^ (srow0 & 7)) * 8;
  const us* Wg = W + (size_t)(colBase + srow0) * 1024 + spos8;

  f32x4 acc[4][4];
#pragma unroll
  for (int i = 0; i < 4; i++)
#pragma unroll
    for (int j = 0; j < 4; j++) acc[i][j] = (f32x4){0.f, 0.f, 0.f, 0.f};

  for (int k0 = 0; k0 < 1024; k0 += 64) {
#pragma unroll
    for (int i = 0; i < 4; i++)
      gl_lds16(Wg + (size_t)i * 32 * 1024 + k0, &Ws[(i * 256 + wave * 64) * 8]);
    if (MODE == 3) {
      const us* Xg = (const us*)Xv + (size_t)(rowBase + srow0) * 1024 + spos8;
#pragma unroll
      for (int i = 0; i < 4; i++)
        gl_lds16(Xg + (size_t)i * 32 * 1024 + k0, &Xs[(i * 256 + wave * 64) * 8]);
    } else {
      const float* Xf = (const float*)Xv;
#pragma unroll
      for (int i = 0; i < 4; i++) {
        int g = t + 256 * i;            // 0..1023
        int r = g >> 3, c = g & 7;
        const float* p = Xf + (size_t)(rowBase + r) * 1024 + k0 + c * 8;
        float4 a = *(const float4*)p;
        float4 bq = *(const float4*)(p + 4);
        unsigned int p0 = pk2(a.x, a.y), p1 = pk2(a.z, a.w);
        unsigned int p2 = pk2(bq.x, bq.y), p3 = pk2(bq.z, bq.w);
        *(ui4v*)&Xs[r * 64 + ((c ^ (r & 7)) << 3)] = (ui4v){p0, p1, p2, p3};
      }
    }
    __syncthreads();

#pragma unroll
    for (int ks = 0; ks < 2; ks++) {
      bf16x8 xf[4], wf[4];
#pragma unroll
      for (int a = 0; a < 4; a++) {
        int rr = wm * 64 + a * 16 + l16;
        xf[a] = *(const bf16x8*)&Xs[rr * 64 + ((((ks << 2) | q4)) ^ (rr & 7)) * 8];
      }
#pragma unroll
      for (int a = 0; a < 4; a++) {
        int rr = wn * 64 + a * 16 + l16;
        wf[a] = *(const bf16x8*)&Ws[rr * 64 + ((((ks << 2) | q4)) ^ (rr & 7)) * 8];
      }
#pragma unroll
      for (int i = 0; i < 4; i++)
#pragma unroll
        for (int j = 0; j < 4; j++) {
          if (MODE == 0)  // swapped: A=W (rows=cols), B=X (rows=n)
            acc[i][j] = __builtin_amdgcn_mfma_f32_16x16x32_bf16(wf[i], xf[j], acc[i][j], 0, 0, 0);
          else
            acc[i][j] = __builtin_amdgcn_mfma_f32_16x16x32_bf16(xf[i], wf[j], acc[i][j], 0, 0, 0);
        }
    }
    __syncthreads();
  }

  if (MODE == 3) {
    // direct fp32 row-major stores (full lines across l16)
#pragma unroll
    for (int j = 0; j < 4; j++) {
      int col = colBase + wn * 64 + j * 16 + l16;
      float bv = bias[col];
#pragma unroll
      for (int i = 0; i < 4; i++) {
        int row0 = rowBase + wm * 64 + i * 16 + q4 * 4;
#pragma unroll
        for (int r = 0; r < 4; r++)
          ((float*)Yv)[(size_t)(row0 + r) * 1024 + col] = acc[i][j][r] + bv;
      }
    }
  } else if (MODE == 1 || MODE == 2) {
    // acc[i=m-group][j=col-group]: row<->m, col<->w-col. Stage to tile[col][m].
#pragma unroll
    for (int j = 0; j < 4; j++) {
      int cl = wn * 64 + j * 16 + l16;
      float bv = bias[colBase + cl];
#pragma unroll
      for (int i = 0; i < 4; i++) {
        int m0 = wm * 64 + i * 16 + q4 * 4;
        us4v pk;
#pragma unroll
        for (int r = 0; r < 4; r++) {
          float y = acc[i][j][r] + bv;
          if (MODE == 1) y = (y > 0.f) ? (y + 1.f) : __expf(y);
          pk[r] = f2bf(y);
        }
        int cm = m0 >> 3, sub = (m0 >> 2) & 1;
        *(us4v*)&tile[cl * 128 + ((cm ^ (cl & 15)) << 3) + sub * 4] = pk;
      }
    }
    __syncthreads();
    // cooperative transposed store: 256B contiguous per 16 lanes
#pragma unroll
    for (int p = 0; p < 8; p++) {
      int cl = p * 16 + (t >> 4);
      int cm = t & 15;
      us8v v = *(const us8v*)&tile[cl * 128 + ((cm ^ (cl & 15)) << 3)];
      int gc = colBase + cl;
      int h = gc >> 6, dd = gc & 63;
      int m0g = (rowBase & 4095) + cm * 8;
      *(us8v*)&((us*)Yv)[(((size_t)((b * 16 + h) * 64 + dd)) << 12) + m0g] = v;
    }
  } else {
    // ---- MODE 0: fused attention epilogue ----
    // acc[i=wcol-group][j=n-group]: row<->col (4 consecutive/lane), col<->n.
    // 1) phi -> qtile[n][col], swizzled 16B chunks
#pragma unroll
    for (int i = 0; i < 4; i++) {
      int c0 = wn * 64 + i * 16 + q4 * 4;
      float4 bv = *(const float4*)&fbuf[384 + c0];
      int cq = c0 >> 3, sub = (c0 >> 2) & 1;
#pragma unroll
      for (int j = 0; j < 4; j++) {
        int nl = wm * 64 + j * 16 + l16;
        us4v pk;
        float bvr[4] = {bv.x, bv.y, bv.z, bv.w};
#pragma unroll
        for (int r = 0; r < 4; r++) {
          float y = acc[i][j][r] + bvr[r];
          y = (y > 0.f) ? (y + 1.f) : __expf(y);
          pk[r] = f2bf(y);
        }
        *(us4v*)&tile[nl * 128 + ((cq ^ (nl & 15)) << 3) + sub * 4] = pk;
      }
    }
    __syncthreads();
    // 2) invden[hh*128+n] = 1/(q[n]·z[hh] + eps)
    {
      int nl = t & 127, hh = t >> 7;
      float s = 0.f;
#pragma unroll
      for (int c8 = 0; c8 < 8; c8++) {
        int pos = (hh * 8 + c8) ^ (nl & 15);
        us8v v = *(const us8v*)&tile[nl * 128 + (pos << 3)];
#pragma unroll
        for (int e = 0; e < 8; e++) s += bf2f(v[e]) * fbuf[256 + hh * 64 + c8 * 8 + e];
      }
      fbuf[hh * 128 + nl] = 1.0f / (s + EPS);
    }
    // 3) num = q @ kv : A=kvs rows e, B=qtile rows n
    f32x4 a2[4][4];
#pragma unroll
    for (int i = 0; i < 4; i++)
#pragma unroll
      for (int j = 0; j < 4; j++) a2[i][j] = (f32x4){0.f, 0.f, 0.f, 0.f};
#pragma unroll
    for (int ks = 0; ks < 2; ks++) {
      bf16x8 kf[4], qf[4];
#pragma unroll
      for (int a = 0; a < 4; a++)
        kf[a] = *(const bf16x8*)&kvs[wn * 4608 + (a * 16 + l16) * 72 + ks * 32 + q4 * 8];
#pragma unroll
      for (int a = 0; a < 4; a++) {
        int nl = wm * 64 + a * 16 + l16;
        int cq = wn * 8 + ks * 4 + q4;
        qf[a] = *(const bf16x8*)&tile[nl * 128 + ((cq ^ (nl & 15)) << 3)];
      }
#pragma unroll
      for (int i = 0; i < 4; i++)
#pragma unroll
        for (int j = 0; j < 4; j++)
          a2[i][j] = __builtin_amdgcn_mfma_f32_16x16x32_bf16(kf[i], qf[j], a2[i][j], 0, 0, 0);
    }
    __syncthreads();  // all qtile reads + invden writes complete
    // 4) scaled write back: a2[i=e-group][j=n-group], row<->e, col<->n
#pragma unroll
    for (int i = 0; i < 4; i++) {
      int c0 = wn * 64 + i * 16 + q4 * 4;
      int cq = c0 >> 3, sub = (c0 >> 2) & 1;
#pragma unroll
      for (int j = 0; j < 4; j++) {
        int nl = wm * 64 + j * 16 + l16;
        float iv = fbuf[wn * 128 + nl];
        us4v pk;
#pragma unroll
        for (int r = 0; r < 4; r++) pk[r] = f2bf(a2[i][j][r] * iv);
        *(us4v*)&tile[nl * 128 + ((cq ^ (nl & 15)) << 3) + sub * 4] = pk;
      }
    }
    __syncthreads();
    // 5) coalesced row-major store of attn
#pragma unroll
    for (int p = 0; p < 8; p++) {
      int nl = p * 16 + (t >> 4);
      int cc = t & 15;
      us8v v = *(const us8v*)&tile[nl * 128 + ((cc ^ (nl & 15)) << 3)];
      *(us8v*)&((us*)Yv)[(size_t)(rowBase + nl) * 1024 + colBase + cc * 8] = v;
    }
  }
}

// ---------------------------------------------------------------------------
// kv stage 1: partial kv[e][d] over a 512-m slab + z partials. 512 blocks.
// ---------------------------------------------------------------------------
__global__ __launch_bounds__(256) void kv_stage1(const us* __restrict__ kt,
                                                 const us* __restrict__ vt,
                                                 float* __restrict__ part,
                                                 float* __restrict__ zpart) {
  __shared__ float red[4][4096];
  __shared__ float zred[4][64][4];

  const int blk = blockIdx.x;
  const int bh = blk >> 3, split = blk & 7;
  const int t = threadIdx.x;
  const int w = t >> 6, lane = t & 63;
  const int q4 = lane >> 4, l16 = lane & 15;
  const us* ktb = kt + (size_t)bh * 64 * 4096;
  const us* vtb = vt + (size_t)bh * 64 * 4096;
  const int mbeg = split * 512 + w * 128;

  f32x4 acc[4][4];
#pragma unroll
  for (int i = 0; i < 4; i++)
#pragma unroll
    for (int j = 0; j < 4; j++) acc[i][j] = (f32x4){0.f, 0.f, 0.f, 0.f};
  float zacc[4] = {0.f, 0.f, 0.f, 0.f};

  for (int m0 = mbeg; m0 < mbeg + 128; m0 += 32) {
    bf16x8 af[4], bfr[4];
#pragma unroll
    for (int i = 0; i < 4; i++)
      af[i] = *(const bf16x8*)&vtb[(size_t)(i * 16 + l16) * 4096 + m0 + q4 * 8];
#pragma unroll
    for (int j = 0; j < 4; j++) {
      us8v ub = *(const us8v*)&ktb[(size_t)(j * 16 + l16) * 4096 + m0 + q4 * 8];
      bfr[j] = __builtin_bit_cast(bf16x8, ub);
#pragma unroll
      for (int e = 0; e < 8; e++) zacc[j] += bf2f(ub[e]);
    }
#pragma unroll
    for (int i = 0; i < 4; i++)
#pragma unroll
      for (int j = 0; j < 4; j++)
        acc[i][j] = __builtin_amdgcn_mfma_f32_16x16x32_bf16(af[i], bfr[j], acc[i][j], 0, 0, 0);
  }

#pragma unroll
  for (int i = 0; i < 4; i++)
#pragma unroll
    for (int j = 0; j < 4; j++)
#pragma unroll
      for (int r = 0; r < 4; r++)
        red[w][(i * 16 + q4 * 4 + r) * 64 + j * 16 + l16] = acc[i][j][r];
#pragma unroll
  for (int j = 0; j < 4; j++) zred[w][j * 16 + l16][q4] = zacc[j];
  __syncthreads();

  float* pb = part + (size_t)blk * 4096;
#pragma unroll
  for (int i = 0; i < 16; i++) {
    int idx = t + 256 * i;
    pb[idx] = red[0][idx] + red[1][idx] + red[2][idx] + red[3][idx];
  }
  if (t < 64) {
    float s = 0.f;
#pragma unroll
    for (int w2 = 0; w2 < 4; w2++)
#pragma unroll
      for (int q = 0; q < 4; q++) s += zred[w2][t][q];
    zpart[blk * 64 + t] = s;
  }
}

// stage 2: reduce 8 split-partials -> kv bf16 [e][d] + z fp32. 64 blocks.
__global__ __launch_bounds__(256) void kv_stage2(const float* __restrict__ part,
                                                 const float* __restrict__ zpart,
                                                 us* __restrict__ kvb,
                                                 float* __restrict__ z) {
  const int bh = blockIdx.x;
  const int t = threadIdx.x;
  const float* p0 = part + (size_t)bh * 8 * 4096;
#pragma unroll
  for (int i = 0; i < 16; i++) {
    int idx = t + 256 * i;
    float s = 0.f;
#pragma unroll
    for (int q = 0; q < 8; q++) s += p0[q * 4096 + idx];
    kvb[((size_t)bh << 12) + idx] = f2bf(s);
  }
  if (t < 64) {
    const float* zp = zpart + (size_t)bh * 8 * 64;
    float s = 0.f;
#pragma unroll
    for (int q = 0; q < 8; q++) s += zp[q * 64 + t];
    z[bh * 64 + t] = s;
  }
}

// ---------------------------------------------------------------------------
extern "C" void kernel_launch(void* const* d_in, const int* in_sizes, int n_in,
                              void* d_out, int out_size, void* d_ws, size_t ws_size,
                              hipStream_t stream) {
  const float* queries = (const float*)d_in[0];
  const float* keys    = (const float*)d_in[1];
  const float* values  = (const float*)d_in[2];
  const float* wq = (const float*)d_in[3];
  const float* bq = (const float*)d_in[4];
  const float* wk = (const float*)d_in[5];
  const float* bk = (const float*)d_in[6];
  const float* wv = (const float*)d_in[7];
  const float* bv = (const float*)d_in[8];
  const float* wo = (const float*)d_in[9];
  const float* bo = (const float*)d_in[10];

  char* ws = (char*)d_ws;
  const size_t TB = (size_t)16384 * 1024 * 2;  // 33.55 MB big bf16 buffer
  us* kt_buf   = (us*)(ws);
  us* vt_buf   = (us*)(ws + TB);
  us* attn_buf = (us*)(ws + 2 * TB);
  // part/zpart alias attn_buf (dead before attention writes)
  float* part  = (float*)attn_buf;                       // 512*4096*4 = 8.4 MB
  float* zpart = part + (size_t)512 * 4096;              // 512*64*4
  us* wqb = (us*)(ws + 3 * TB);
  us* wkb = wqb + (size_t)1024 * 1024;
  us* wvb = wkb + (size_t)1024 * 1024;
  us* wob = wvb + (size_t)1024 * 1024;
  us* kvb = wob + (size_t)1024 * 1024;                   // 64*4096 bf16
  float* z = (float*)(kvb + (size_t)64 * 4096);          // 4096 fp32

  const int GRID_W = 1024 * 1024 / 2048;  // 512

  conv_bf16<<<GRID_W, 256, 0, stream>>>(wq, wqb);
  conv_bf16<<<GRID_W, 256, 0, stream>>>(wk, wkb);
  conv_bf16<<<GRID_W, 256, 0, stream>>>(wv, wvb);
  conv_bf16<<<GRID_W, 256, 0, stream>>>(wo, wob);

  proj_gemm<1><<<1024, 256, 0, stream>>>((const void*)keys, wkb, bk, (void*)kt_buf, nullptr, nullptr);
  proj_gemm<2><<<1024, 256, 0, stream>>>((const void*)values, wvb, bv, (void*)vt_buf, nullptr, nullptr);
  kv_stage1<<<512, 256, 0, stream>>>(kt_buf, vt_buf, part, zpart);
  kv_stage2<<<64, 256, 0, stream>>>(part, zpart, kvb, z);
  proj_gemm<0><<<1024, 256, 0, stream>>>((const void*)queries, wqb, bq, (void*)attn_buf, kvb, z);
  proj_gemm<3><<<1024, 256, 0, stream>>>((const void*)attn_buf, wob, bo, d_out, nullptr, nullptr);
}